// Round 9
// baseline (340.448 us; speedup 1.0000x reference)
//
#include <hip/hip_runtime.h>
#include <math.h>

#define N_ROWS 200000
#define D 200
#define OUT1 300
#define OUT2 400

#define S1B 1000                    // stage-1 blocks per branch
#define Q_TOTAL 10000000            // float4s per branch (200000*200/4)
#define Q_STRIDE (S1B * 256)        // 256,000 float4s per grid pass
                                    // float stride 1,024,000 % 200 == 0 ->
                                    // each thread's float4 = fixed column quad

using f32x4 = __attribute__((ext_vector_type(4))) float;

// ---------------------------------------------------------------------------
// Stage 1: column-sum of [N_ROWS, D] f32 (branch = blockIdx.y).
// Flat 4096B-aligned walk (all 256 lanes, 1KB aligned wave-loads) + NT loads.
// Thread t of block b always reads column-quad q = (6b + t) % 50.
// partial layout: [2][S1B][D] floats (float4-coalesced 800B store/block).
// ---------------------------------------------------------------------------
__global__ __launch_bounds__(256)
void colsum_kernel(const float* __restrict__ userH,
                   const float* __restrict__ postH,
                   float* __restrict__ partial)
{
    const int br  = blockIdx.y;
    const int bid = blockIdx.x;
    const int t   = threadIdx.x;
    const f32x4* __restrict__ H4 =
        reinterpret_cast<const f32x4*>(br ? postH : userH);

    f32x4 acc = {0.f, 0.f, 0.f, 0.f};
    int idx = bid * 256 + t;
    // 39 full passes (39 * 256000 = 9,984,000), then guarded tail (16,000).
    for (int k = 0; k < 39; ++k) {
        acc += __builtin_nontemporal_load(H4 + idx);
        idx += Q_STRIDE;
    }
    if (idx < Q_TOTAL)
        acc += __builtin_nontemporal_load(H4 + idx);

    // Combine 256 thread-accumulators into 50 column-quads via rotation table.
    __shared__ f32x4 part[6][50];   // 4.8 KB
    const int q = (6 * bid + t) % 50;   // this thread's column quad
    if (t < 50) part[5][t] = (f32x4){0.f, 0.f, 0.f, 0.f}; // group 5 sparse
    __syncthreads();
    part[t / 50][q] = acc;           // distinct slots within each group
    __syncthreads();

    if (t < 50) {
        f32x4 s = part[0][t] + part[1][t] + part[2][t]
                + part[3][t] + part[4][t] + part[5][t];
        reinterpret_cast<f32x4*>(partial)[((size_t)br * S1B + bid) * 50 + t] = s;
    }
}

// ---------------------------------------------------------------------------
// Stage 2a: partial[2][1000][200] -> partial2[2][10][200]. 20 blocks (10 x 2).
// Block (chunk, br) reduces 100 block-rows; 200 active threads.
// ---------------------------------------------------------------------------
__global__ __launch_bounds__(256)
void reduce_kernel(const float* __restrict__ partial,
                   float* __restrict__ partial2)
{
    const int chunk = blockIdx.x;   // 0..9
    const int br    = blockIdx.y;
    const int t     = threadIdx.x;
    const int q  = t % 50;
    const int sr = t / 50;          // 0..3 active (t < 200)

    f32x4 acc = {0.f, 0.f, 0.f, 0.f};
    if (t < 200) {
        const f32x4* __restrict__ P =
            reinterpret_cast<const f32x4*>(partial) + (size_t)br * S1B * 50;
        const int row0 = chunk * 100 + sr;
        #pragma unroll 5
        for (int k = 0; k < 25; ++k)
            acc += P[(size_t)(row0 + 4 * k) * 50 + q];
    }

    __shared__ f32x4 part[4][50];
    if (t < 200) part[sr][q] = acc;
    __syncthreads();

    if (t < 50) {
        const f32x4 s = part[0][t] + part[1][t] + part[2][t] + part[3][t];
        reinterpret_cast<f32x4*>(partial2)[((size_t)br * 10 + chunk) * 50 + t] = s;
    }
}

// ---------------------------------------------------------------------------
// Stage 2b: g1 = relu(m @ W1 + b1). 12 blocks (6 x 2); block owns 50 outputs.
// m recomputed per block from partial2. Dot-200 split 4 ways per output.
// ---------------------------------------------------------------------------
__global__ __launch_bounds__(256)
void g1_kernel(const float* __restrict__ partial2,
               const float* __restrict__ W1u, const float* __restrict__ b1u,
               const float* __restrict__ W1p, const float* __restrict__ b1p,
               float* __restrict__ g1)
{
    const int jb = blockIdx.x;      // 0..5 -> outputs jb*50 .. jb*50+49
    const int br = blockIdx.y;
    const float* __restrict__ W1 = br ? W1p : W1u;
    const float* __restrict__ b1 = br ? b1p : b1u;
    const int t = threadIdx.x;

    __shared__ float m[D];
    if (t < D) {
        float s = 0.f;
        #pragma unroll
        for (int ch = 0; ch < 10; ++ch)
            s += partial2[((size_t)br * 10 + ch) * D + t];
        m[t] = s * (1.0f / (float)N_ROWS);
    }
    __syncthreads();

    const int j   = t % 50;
    const int seg = t / 50;         // 0..3 active (t < 200)
    float p = 0.f;
    if (t < 200) {
        const int c0 = seg * 50;
        for (int c = c0; c < c0 + 50; ++c)
            p += m[c] * W1[(size_t)c * OUT1 + jb * 50 + j];
    }
    __shared__ float pj[4][50];
    if (t < 200) pj[seg][j] = p;
    __syncthreads();

    if (t < 50) {
        const float s = b1[jb * 50 + t] + pj[0][t] + pj[1][t] + pj[2][t] + pj[3][t];
        g1[(size_t)br * OUT1 + jb * 50 + t] = fmaxf(s, 0.f);
    }
}

// ---------------------------------------------------------------------------
// Stage 2c: g2 = g1 @ W2 + b2. 16 blocks (8 x 2); block owns 50 outputs.
// Dot-300 split into 4 segments of 75 across threads.
// ---------------------------------------------------------------------------
__global__ __launch_bounds__(256)
void g2_kernel(const float* __restrict__ g1,
               const float* __restrict__ W2u, const float* __restrict__ b2u,
               const float* __restrict__ W2p, const float* __restrict__ b2p,
               float* __restrict__ g2)
{
    const int kb = blockIdx.x;      // 0..7 -> outputs kb*50 .. kb*50+49
    const int br = blockIdx.y;
    const float* __restrict__ W2 = br ? W2p : W2u;
    const float* __restrict__ b2 = br ? b2p : b2u;
    const int t = threadIdx.x;

    __shared__ float g[OUT1];
    for (int i = t; i < OUT1; i += 256) g[i] = g1[(size_t)br * OUT1 + i];
    __syncthreads();

    const int k   = t % 50;
    const int seg = t / 50;         // 0..3 active (t < 200)
    float p = 0.f;
    if (t < 200) {
        const int j0 = seg * 75;
        for (int j = j0; j < j0 + 75; ++j)
            p += g[j] * W2[(size_t)j * OUT2 + kb * 50 + k];
    }
    __shared__ float pk[4][50];
    if (t < 200) pk[seg][k] = p;
    __syncthreads();

    if (t < 50) {
        g2[(size_t)br * OUT2 + kb * 50 + t] =
            b2[kb * 50 + t] + pk[0][t] + pk[1][t] + pk[2][t] + pk[3][t];
    }
}

// ---------------------------------------------------------------------------
// Stage 2d: softmax per branch -> combine -> dot W_out -> sigmoid. 1 block,
// 128 threads: wave 0 -> branch 0, wave 1 -> branch 1.
// ---------------------------------------------------------------------------
__global__ __launch_bounds__(128)
void finish_kernel(const float* __restrict__ g2,
                   const float* __restrict__ Wout, const float* __restrict__ bout,
                   float* __restrict__ out)
{
    __shared__ float sm[2][OUT2];
    const int wave = threadIdx.x >> 6;
    const int lane = threadIdx.x & 63;
    const int br   = wave;

    float mx = -INFINITY;
    for (int k = lane; k < OUT2; k += 64)
        mx = fmaxf(mx, g2[(size_t)br * OUT2 + k]);
    #pragma unroll
    for (int off = 32; off > 0; off >>= 1) mx = fmaxf(mx, __shfl_xor(mx, off));

    float sum = 0.f;
    for (int k = lane; k < OUT2; k += 64) {
        const float e = expf(g2[(size_t)br * OUT2 + k] - mx);
        sm[br][k] = e;
        sum += e;
    }
    #pragma unroll
    for (int off = 32; off > 0; off >>= 1) sum += __shfl_xor(sum, off);
    const float inv = 1.0f / sum;
    for (int k = lane; k < OUT2; k += 64) sm[br][k] *= inv;
    __syncthreads();

    if (wave == 0) {
        float s = 0.f;
        for (int k = lane; k < OUT2; k += 64)
            s += (sm[0][k] + sm[1][k]) * Wout[k];
        #pragma unroll
        for (int off = 32; off > 0; off >>= 1) s += __shfl_xor(s, off);
        if (lane == 0)
            out[0] = 1.0f / (1.0f + expf(-(s + bout[0])));
    }
}

// ---------------------------------------------------------------------------
extern "C" void kernel_launch(void* const* d_in, const int* in_sizes, int n_in,
                              void* d_out, int out_size, void* d_ws, size_t ws_size,
                              hipStream_t stream) {
    const float* userH = (const float*)d_in[0];
    const float* postH = (const float*)d_in[1];
    const float* W1u   = (const float*)d_in[2];
    const float* b1u   = (const float*)d_in[3];
    const float* W2u   = (const float*)d_in[4];
    const float* b2u   = (const float*)d_in[5];
    const float* W1p   = (const float*)d_in[6];
    const float* b1p   = (const float*)d_in[7];
    const float* W2p   = (const float*)d_in[8];
    const float* b2p   = (const float*)d_in[9];
    const float* Wout  = (const float*)d_in[10];
    const float* bout  = (const float*)d_in[11];

    float* ws       = (float*)d_ws;
    float* partial  = ws;              // 2*1000*200 = 400,000 f (16B-aligned)
    float* partial2 = ws + 400000;     // 2*10*200   =   4,000 f (16B-aligned)
    float* g1       = ws + 404000;     // 2*300      =     600 f
    float* g2       = ws + 404600;     // 2*400      =     800 f

    colsum_kernel<<<dim3(S1B, 2), 256, 0, stream>>>(userH, postH, partial);
    reduce_kernel<<<dim3(10, 2),  256, 0, stream>>>(partial, partial2);
    g1_kernel    <<<dim3(6, 2),   256, 0, stream>>>(partial2, W1u, b1u, W1p, b1p, g1);
    g2_kernel    <<<dim3(8, 2),   256, 0, stream>>>(g1, W2u, b2u, W2p, b2p, g2);
    finish_kernel<<<1,            128, 0, stream>>>(g2, Wout, bout, (float*)d_out);
}